// Round 13
// baseline (281.848 us; speedup 1.0000x reference)
//
#include <hip/hip_runtime.h>
#include <hip/hip_bf16.h>

#define NN 50000
#define NR 8
#define DIM 128
#define NE 800000
#define TM 32     // targets per block
#define PAD 136   // A-tile row stride in bf16 (128 + 8): R0-proven banking
#define CAP 1024  // per-block bucket capacity (mean 512, Poisson -> overflow prob ~0; guarded)
#define NB 1563   // ceil(NN/TM)

using floatx4 = __attribute__((ext_vector_type(4))) float;
using bf16x8  = __attribute__((ext_vector_type(8))) __bf16;

// ---------------- workspace layout (in floats) ----------------
// zeroed region: [0, 426160) = wsum + S2X1 + blkcnt
#define OFF_WSUM  0u         // 400000: wsum[r*NN+h] fp32 atomic accum
#define OFF_S2    400000u    // 1152: S2[1024] + X1[128]
#define OFF_BCNT  401152u    // 1563*16 ints: per-block bucket counters (64B stride)
#define OFF_BBUF  426160u    // 1563*1024 ints: per-block edge buckets, pk = (lseg<<17)|head
#define OFF_XB    2026672u   // 6.4M bf16: x_emb in bf16 (16B aligned)
#define OFF_WF    5226672u   // 9*2048*8 bf16: weights in MFMA frag order
#define OFF_S2P   5300400u   // NB*1152: per-block S2/X1 partials
// total 7,100,976 floats = 28.4 MB

// ---------------- merged prep: bf16 cast + weight frags + bucket assign ----------------
// bucket key TARGET-MAJOR (R0): lseg = (te&31)*NR + re  -> pk = (lseg<<17)|he
__global__ __launch_bounds__(256) void prep_k(
    const float* __restrict__ x, __bf16* __restrict__ xb,
    const float* __restrict__ W1, const float* __restrict__ root1, __bf16* __restrict__ wf,
    const int* __restrict__ h, const int* __restrict__ r, const int* __restrict__ t,
    int* __restrict__ blkcnt, int* __restrict__ blkbuf)
{
    const int gid = blockIdx.x * 256 + threadIdx.x;
    const int nthr = gridDim.x * 256;

    if (gid < 9 * 2048) {
        int mat = gid >> 11, idx = gid & 2047;
        const float* B = (mat < 8) ? (W1 + (size_t)mat * DIM * DIM) : root1;
        int lt = idx & 63, fid = idx >> 6;
        int s = fid >> 3, nt = fid & 7;
        int n = nt * 16 + (lt & 15);
        int kb = s * 32 + (lt >> 4) * 8;
        bf16x8 v;
#pragma unroll
        for (int j = 0; j < 8; ++j) v[j] = (__bf16)B[(kb + j) * DIM + n];
        *reinterpret_cast<bf16x8*>(wf + ((size_t)mat * 2048 + idx) * 8) = v;
    }
    for (int i = gid; i < NN * DIM / 4; i += nthr) {
        int base = i * 4;
        float4 v = *reinterpret_cast<const float4*>(x + base);
        __bf16 o[4] = {(__bf16)v.x, (__bf16)v.y, (__bf16)v.z, (__bf16)v.w};
        *reinterpret_cast<uint2*>(xb + base) = *reinterpret_cast<uint2*>(o);
    }
    // edge loop: bucket append only (one global atomic per edge)
    for (int i = gid; i < NE / 4; i += nthr) {
        int base = i * 4;
        int4 hv = *reinterpret_cast<const int4*>(h + base);
        int4 rv = *reinterpret_cast<const int4*>(r + base);
        int4 tv = *reinterpret_cast<const int4*>(t + base);
#pragma unroll
        for (int j = 0; j < 4; ++j) {
            int te = (j == 0) ? tv.x : (j == 1) ? tv.y : (j == 2) ? tv.z : tv.w;
            int re = (j == 0) ? rv.x : (j == 1) ? rv.y : (j == 2) ? rv.z : rv.w;
            int he = (j == 0) ? hv.x : (j == 1) ? hv.y : (j == 2) ? hv.z : hv.w;
            int blk = te >> 5;
            int pos = atomicAdd(&blkcnt[blk * 16], 1);
            if (pos < CAP) blkbuf[blk * CAP + pos] = ((((te & 31) * NR) + re) << 17) | he;
        }
    }
}

// ---------------- wsum: bucket-based (R4-proven); block 0 zeroes out[] ----------------
__global__ __launch_bounds__(256) void wsum_k(
    const int* __restrict__ blkcnt, const int* __restrict__ blkbuf, float* __restrict__ wsum,
    float* __restrict__ out)
{
    __shared__ int   lcnt[TM * NR];
    __shared__ float linv[TM * NR];
    const int tid = threadIdx.x;
    if (blockIdx.x == 0 && tid < 128) out[tid] = 0.f;
    int n = blkcnt[blockIdx.x * 16];
    if (n > CAP) n = CAP;
    const int* gbuf = blkbuf + (size_t)blockIdx.x * CAP;
    lcnt[tid] = 0;
    __syncthreads();
    int pk0 = -1, pk1 = -1, pk2 = -1, pk3 = -1;
    if (tid < n)       { pk0 = gbuf[tid];       atomicAdd(&lcnt[pk0 >> 17], 1); }
    if (tid + 256 < n) { pk1 = gbuf[tid + 256]; atomicAdd(&lcnt[pk1 >> 17], 1); }
    if (tid + 512 < n) { pk2 = gbuf[tid + 512]; atomicAdd(&lcnt[pk2 >> 17], 1); }
    if (tid + 768 < n) { pk3 = gbuf[tid + 768]; atomicAdd(&lcnt[pk3 >> 17], 1); }
    __syncthreads();
    int c = lcnt[tid];
    linv[tid] = 1.0f / (float)(c > 1 ? c : 1);
    __syncthreads();
    if (pk0 >= 0) atomicAdd(&wsum[(size_t)((pk0 >> 17) & 7) * NN + (pk0 & 0x1FFFF)], linv[pk0 >> 17]);
    if (pk1 >= 0) atomicAdd(&wsum[(size_t)((pk1 >> 17) & 7) * NN + (pk1 & 0x1FFFF)], linv[pk1 >> 17]);
    if (pk2 >= 0) atomicAdd(&wsum[(size_t)((pk2 >> 17) & 7) * NN + (pk2 & 0x1FFFF)], linv[pk2 >> 17]);
    if (pk3 >= 0) atomicAdd(&wsum[(size_t)((pk3 >> 17) & 7) * NN + (pk3 & 0x1FFFF)], linv[pk3 >> 17]);
}

// ---------------- fused layer 1 + layer-2 partials: local CSR + depth-2 walk ----------------
// (256,4) + depth-2 + 64 VGPR is a measured local optimum; closed directions:
//   R6: min-waves 6 -> VGPR crushed to 40, 266MB spill churn, 140us
//   R8: depth-3 -> scratch spill at fixed 64 VGPR (FETCH +75MB, WRITE +65MB), 130us
//   R5: masked unconditional loads -> +2us (no vmcnt win)
//   R1/R2/R3/R9: restructures -> 2x losses
//   R12: inline-asm PFROW (4 outstanding same-dest loads) -> runtime abort. NO INLINE ASM.
// R11: shfl-scan prologue (16 barriers -> 2): 89.6 -> 84.4us.
// R13 CHANGE: L2-warm prefetch via PLAIN C++ int touches (offsets 0,128 = both 128B L2
// lines of the 256B row) summed into pf, kept alive by the no-op sink
// asm volatile(""::"v"(pf)) (guide rule #17 -- no instruction emitted). Loads overlap the
// CSR-build phase; the walk's ~45% L2 misses become hits.
__global__ __launch_bounds__(256, 4) void rgcn_fused_k(
    const int* __restrict__ blkcnt, const int* __restrict__ blkbuf,
    const __bf16* __restrict__ xb, const __bf16* __restrict__ wf,
    const float* __restrict__ b1, const float* __restrict__ wsum,
    float* __restrict__ S2P)
{
    __shared__ __attribute__((aligned(16))) __bf16 Atile[2][TM * PAD];  // 17.4 KB (red reuse)
    __shared__ int   loffs[TM * NR + 1];
    __shared__ int   lcnt[TM * NR];
    __shared__ int   cursor[TM * NR];
    __shared__ float invl[TM * NR];
    __shared__ float wsl[NR][TM];
    __shared__ int   wsumS[4];          // per-wave scan sums
    __shared__ int   pkd[CAP];          // heads, sorted by local segment
    const int tid = threadIdx.x;
    const int wave = tid >> 6, lane = tid & 63, quad = lane >> 4;
    const int slot = tid >> 4, sl = tid & 15;   // 16 gather slots x 16 lanes
    const int tbase = blockIdx.x * TM;

    // ---- local CSR build (+ L2-warm touches of the gather rows) ----
    int n = blkcnt[blockIdx.x * 16];
    if (n > CAP) n = CAP;
    const int* gbuf = blkbuf + (size_t)blockIdx.x * CAP;
    lcnt[tid] = 0;
    __syncthreads();
    int pk0 = -1, pk1 = -1, pk2 = -1, pk3 = -1;
    int pf = 0;
    if (tid < n)       { pk0 = gbuf[tid];       atomicAdd(&lcnt[pk0 >> 17], 1);
                         const int* pp = (const int*)(xb + (size_t)(pk0 & 0x1FFFF) * DIM);
                         pf += pp[0] + pp[32]; }
    if (tid + 256 < n) { pk1 = gbuf[tid + 256]; atomicAdd(&lcnt[pk1 >> 17], 1);
                         const int* pp = (const int*)(xb + (size_t)(pk1 & 0x1FFFF) * DIM);
                         pf += pp[0] + pp[32]; }
    if (tid + 512 < n) { pk2 = gbuf[tid + 512]; atomicAdd(&lcnt[pk2 >> 17], 1);
                         const int* pp = (const int*)(xb + (size_t)(pk2 & 0x1FFFF) * DIM);
                         pf += pp[0] + pp[32]; }
    if (tid + 768 < n) { pk3 = gbuf[tid + 768]; atomicAdd(&lcnt[pk3 >> 17], 1);
                         const int* pp = (const int*)(xb + (size_t)(pk3 & 0x1FFFF) * DIM);
                         pf += pp[0] + pp[32]; }
    asm volatile("" :: "v"(pf));   // no-op sink: keeps the warm-touches live (rule #17)
    __syncthreads();
    int v = lcnt[tid];
    // wave-level inclusive scan (shfl, barrier-free) + cross-wave offset (2 barriers total)
    int incl = v;
#pragma unroll
    for (int off = 1; off < 64; off <<= 1) {
        int up = __shfl_up(incl, off, 64);
        if (lane >= off) incl += up;
    }
    if (lane == 63) wsumS[wave] = incl;
    __syncthreads();
    int woff = 0;
#pragma unroll
    for (int w = 0; w < 3; ++w) woff += (w < wave) ? wsumS[w] : 0;
    incl += woff;
    loffs[tid + 1] = incl;               // inclusive
    if (tid == 0) loffs[0] = 0;
    cursor[tid] = incl - v;              // exclusive
    invl[tid] = 1.0f / (float)(v > 1 ? v : 1);
    {
        int rr = tid >> 5, nn = tbase + (tid & 31);
        wsl[rr][tid & 31] = (nn < NN) ? wsum[rr * NN + nn] : 0.f;
    }
    __syncthreads();
    if (pk0 >= 0) { int p = atomicAdd(&cursor[pk0 >> 17], 1); pkd[p] = pk0 & 0x1FFFF; }
    if (pk1 >= 0) { int p = atomicAdd(&cursor[pk1 >> 17], 1); pkd[p] = pk1 & 0x1FFFF; }
    if (pk2 >= 0) { int p = atomicAdd(&cursor[pk2 >> 17], 1); pkd[p] = pk2 & 0x1FFFF; }
    if (pk3 >= 0) { int p = atomicAdd(&cursor[pk3 >> 17], 1); pkd[p] = pk3 & 0x1FFFF; }
    __syncthreads();

    floatx4 C[4];
#pragma unroll
    for (int i = 0; i < 4; ++i) C[i] = (floatx4)0.f;
    const int arow = (wave & 1) * 16 + (lane & 15);   // wave row-strip
    const int ntg0 = (wave >> 1) * 4;                 // wave col-strip (4 nt each)

    // ---- 4 term-pairs: 4 depth-2-pipelined walks (2 rows x 2 terms), 2 A-tiles ----
    for (int tp = 0; tp < 4; ++tp) {
        int st[4], ln[4];
        float a[4][8];
#pragma unroll
        for (int q = 0; q < 4; ++q) {
            int j = (slot + (q >> 1) * 16) * 8 + tp * 2 + (q & 1);
            st[q] = loffs[j];
            ln[q] = loffs[j + 1] - loffs[j];
#pragma unroll
            for (int k = 0; k < 8; ++k) a[q][k] = 0.f;
        }
        int mx = max(max(ln[0], ln[1]), max(ln[2], ln[3]));
        if (mx > 0) {
            bf16x8 ycur[4];
#pragma unroll
            for (int q = 0; q < 4; ++q) {
                if (0 < ln[q]) {
                    int he = pkd[st[q]];
                    ycur[q] = *reinterpret_cast<const bf16x8*>(xb + (size_t)he * DIM + sl * 8);
                }
            }
            for (int p = 0; p < mx; ++p) {
                bf16x8 ynext[4];
#pragma unroll
                for (int q = 0; q < 4; ++q) {
                    if (p + 1 < ln[q]) {
                        int he = pkd[st[q] + p + 1];
                        ynext[q] = *reinterpret_cast<const bf16x8*>(xb + (size_t)he * DIM + sl * 8);
                    }
                }
#pragma unroll
                for (int q = 0; q < 4; ++q) {
                    if (p < ln[q]) {
#pragma unroll
                        for (int k = 0; k < 8; ++k) a[q][k] += (float)ycur[q][k];
                    }
                }
#pragma unroll
                for (int q = 0; q < 4; ++q) ycur[q] = ynext[q];
            }
        }
#pragma unroll
        for (int q = 0; q < 4; ++q) {
            int trow = slot + (q >> 1) * 16;
            float sc = invl[trow * 8 + tp * 2 + (q & 1)];
            bf16x8 out;
#pragma unroll
            for (int k = 0; k < 8; ++k) out[k] = (__bf16)(a[q][k] * sc);
            *reinterpret_cast<bf16x8*>(&Atile[q & 1][trow * PAD + sl * 8]) = out;
        }
        __syncthreads();
#pragma unroll
        for (int u = 0; u < 2; ++u) {
            const __bf16* wterm = wf + (size_t)(tp * 2 + u) * 2048 * 8;
#pragma unroll
            for (int s = 0; s < 4; ++s) {
                bf16x8 af = *reinterpret_cast<const bf16x8*>(&Atile[u][arow * PAD + s * 32 + quad * 8]);
#pragma unroll
                for (int nt = 0; nt < 4; ++nt) {
                    bf16x8 bf = *reinterpret_cast<const bf16x8*>(
                        wterm + (size_t)((s * 8 + ntg0 + nt) * 64 + lane) * 8);
                    C[nt] = __builtin_amdgcn_mfma_f32_16x16x32_bf16(af, bf, C[nt], 0, 0, 0);
                }
            }
        }
        __syncthreads();
    }

    // ---- root term: A row = xb[t] ----
#pragma unroll
    for (int i = 0; i < 2; ++i) {
        int trow = slot + i * 16;
        int t = tbase + trow;
        bf16x8 out;
        if (t < NN) {
            out = *reinterpret_cast<const bf16x8*>(xb + (size_t)t * DIM + sl * 8);
        } else {
#pragma unroll
            for (int j = 0; j < 8; ++j) out[j] = (__bf16)0.f;
        }
        *reinterpret_cast<bf16x8*>(&Atile[0][trow * PAD + sl * 8]) = out;
    }
    __syncthreads();
    {
        const __bf16* wterm = wf + (size_t)8 * 2048 * 8;
#pragma unroll
        for (int s = 0; s < 4; ++s) {
            bf16x8 af = *reinterpret_cast<const bf16x8*>(&Atile[0][arow * PAD + s * 32 + quad * 8]);
#pragma unroll
            for (int nt = 0; nt < 4; ++nt) {
                bf16x8 bf = *reinterpret_cast<const bf16x8*>(
                    wterm + (size_t)((s * 8 + ntg0 + nt) * 64 + lane) * 8);
                C[nt] = __builtin_amdgcn_mfma_f32_16x16x32_bf16(af, bf, C[nt], 0, 0, 0);
            }
        }
    }
    __syncthreads();   // Atile dead -> reuse as reduction scratch

    // ---- epilogue: bias + relu in-register, fused S2/X1 block partials ----
    float* red = reinterpret_cast<float*>(&Atile[0][0]);   // [4][576] = 9.2 KB
    const int rowl0 = (wave & 1) * 16 + quad * 4;
    const int colc = lane & 15;
#pragma unroll
    for (int nt = 0; nt < 4; ++nt) {
        float badd = b1[ntg0 * 16 + nt * 16 + colc];
#pragma unroll
        for (int i = 0; i < 4; ++i) C[nt][i] = fmaxf(C[nt][i] + badd, 0.f);
    }
    float rmask[4];
#pragma unroll
    for (int i = 0; i < 4; ++i) rmask[i] = (tbase + rowl0 + i < NN) ? 1.f : 0.f;
#pragma unroll
    for (int nt = 0; nt < 4; ++nt) {
        float p = rmask[0] * C[nt][0] + rmask[1] * C[nt][1] + rmask[2] * C[nt][2] + rmask[3] * C[nt][3];
        p += __shfl_xor(p, 16);
        p += __shfl_xor(p, 32);
        if (quad == 0) red[wave * 576 + nt * 16 + colc] = p;
    }
#pragma unroll
    for (int rr = 0; rr < NR; ++rr) {
        float w0 = wsl[rr][rowl0], w1 = wsl[rr][rowl0 + 1];
        float w2 = wsl[rr][rowl0 + 2], w3 = wsl[rr][rowl0 + 3];
#pragma unroll
        for (int nt = 0; nt < 4; ++nt) {
            float p = w0 * C[nt][0] + w1 * C[nt][1] + w2 * C[nt][2] + w3 * C[nt][3];
            p += __shfl_xor(p, 16);
            p += __shfl_xor(p, 32);
            if (quad == 0) red[wave * 576 + 64 + rr * 64 + nt * 16 + colc] = p;
        }
    }
    __syncthreads();
    for (int j = tid; j < 1152; j += 256) {
        int rr = j >> 7, c = j & 127;          // rr==8 -> X1
        int u = c >> 6, cc = c & 63;
        int o = (rr < 8) ? (64 + rr * 64 + cc) : cc;
        S2P[(size_t)blockIdx.x * 1152 + j] = red[(u * 2) * 576 + o] + red[(u * 2 + 1) * 576 + o];
    }
}

// ---------------- reduce S2P[NB][1152] -> S2X1[1152] (atomic finish, 63 stripes of 25) ----------------
__global__ void s2red_k(const float* __restrict__ S2P, float* __restrict__ S2X1) {
    int cb = blockIdx.x % 5, stripe = blockIdx.x / 5;
    int c = cb * 256 + threadIdx.x;
    if (c >= 1152) return;
    int b0 = stripe * 25, b1 = min(NB, b0 + 25);
    if (b0 >= NB) return;
    float s0 = 0.f, s1 = 0.f;
    int b = b0;
    for (; b + 1 < b1; b += 2) {
        s0 += S2P[(size_t)b * 1152 + c];
        s1 += S2P[(size_t)(b + 1) * 1152 + c];
    }
    if (b < b1) s0 += S2P[(size_t)b * 1152 + c];
    atomicAdd(&S2X1[c], s0 + s1);
}

// ---------------- final: out = (S2.W2 + X1.root2)/N + b2 (72 blocks, R7-proven) ----------------
__global__ __launch_bounds__(256) void final_k(
    const float* __restrict__ S2X1, const float* __restrict__ W2,
    const float* __restrict__ root2, const float* __restrict__ b2, float* __restrict__ out)
{
    __shared__ float red[256];
    const int o = threadIdx.x & 127, jj = threadIdx.x >> 7;   // 2 j-groups of 8
    const int j0 = blockIdx.x * 16 + jj * 8;
    float s = 0.f;
#pragma unroll
    for (int k = 0; k < 8; ++k) {
        int j = j0 + k;
        float v = S2X1[j];
        float w = (j < 1024) ? W2[(size_t)j * DIM + o] : root2[(size_t)(j - 1024) * DIM + o];
        s += v * w;
    }
    red[threadIdx.x] = s;
    __syncthreads();
    if (jj == 0) {
        float add = (red[o] + red[o + 128]) * (1.0f / NN);
        if (blockIdx.x == 0) add += b2[o];
        atomicAdd(&out[o], add);
    }
}

extern "C" void kernel_launch(void* const* d_in, const int* in_sizes, int n_in,
                              void* d_out, int out_size, void* d_ws, size_t ws_size,
                              hipStream_t stream)
{
    const int*   h     = (const int*)d_in[0];
    const int*   r     = (const int*)d_in[1];
    const int*   t     = (const int*)d_in[2];
    const float* x_emb = (const float*)d_in[3];
    const float* W1    = (const float*)d_in[4];
    const float* root1 = (const float*)d_in[5];
    const float* b1    = (const float*)d_in[6];
    const float* W2    = (const float*)d_in[7];
    const float* root2 = (const float*)d_in[8];
    const float* b2    = (const float*)d_in[9];

    float* ws     = (float*)d_ws;
    float* wsum   = ws + OFF_WSUM;
    float* S2     = ws + OFF_S2;      // 1024 S2 + 128 X1 contiguous
    int*   blkcnt = (int*)(ws + OFF_BCNT);
    int*   blkbuf = (int*)(ws + OFF_BBUF);
    __bf16* xb    = (__bf16*)(ws + OFF_XB);
    __bf16* wf    = (__bf16*)(ws + OFF_WF);
    float* S2P    = ws + OFF_S2P;

    // zero wsum + S2X1 + blkcnt (1.7 MB); d_out zeroed inside wsum_k
    hipMemsetAsync(ws, 0, (size_t)426160 * sizeof(float), stream);

    // merged cast + weight-frag + bucket-assign (2048 blocks: fills ~8-blocks/CU residency)
    prep_k<<<2048, 256, 0, stream>>>(x_emb, xb, W1, root1, wf, h, r, t, blkcnt, blkbuf);

    // wsum from buckets (+ out zero)
    wsum_k<<<NB, 256, 0, stream>>>(blkcnt, blkbuf, wsum, (float*)d_out);

    // fused layer 1 + layer-2 partials: converged config + shfl-scan + C++ L2-warm touches
    rgcn_fused_k<<<NB, 256, 0, stream>>>(blkcnt, blkbuf, xb, wf, b1, wsum, S2P);

    s2red_k<<<315, 256, 0, stream>>>(S2P, S2);
    final_k<<<72, 256, 0, stream>>>(S2, W2, root2, b2, (float*)d_out);
}

// Round 14
// 266.406 us; speedup vs baseline: 1.0580x; 1.0580x over previous
//
#include <hip/hip_runtime.h>
#include <hip/hip_bf16.h>

#define NN 50000
#define NR 8
#define DIM 128
#define NE 800000
#define TM 32     // targets per block
#define PAD 136   // A-tile row stride in bf16 (128 + 8): R0-proven banking
#define CAP 1024  // per-block bucket capacity (mean 512, Poisson -> overflow prob ~0; guarded)
#define NB 1563   // ceil(NN/TM)

using floatx4 = __attribute__((ext_vector_type(4))) float;
using bf16x8  = __attribute__((ext_vector_type(8))) __bf16;

// ---------------- workspace layout (in floats) ----------------
// zeroed region: [0, 426160) = wsum + S2X1 + blkcnt
#define OFF_WSUM  0u         // 400000: wsum[r*NN+h] fp32 atomic accum
#define OFF_S2    400000u    // 1152: S2[1024] + X1[128]
#define OFF_BCNT  401152u    // 1563*16 ints: per-block bucket counters (64B stride)
#define OFF_BBUF  426160u    // 1563*1024 ints: per-block edge buckets, pk = (lseg<<17)|head
#define OFF_XB    2026672u   // 6.4M bf16: x_emb in bf16 (16B aligned)
#define OFF_WF    5226672u   // 9*2048*8 bf16: weights in MFMA frag order
#define OFF_S2P   5300400u   // NB*1152: per-block S2/X1 partials
// total 7,100,976 floats = 28.4 MB

// ---------------- merged prep: bf16 cast + weight frags + bucket assign ----------------
// bucket key TARGET-MAJOR (R0): lseg = (te&31)*NR + re  -> pk = (lseg<<17)|he
__global__ __launch_bounds__(256) void prep_k(
    const float* __restrict__ x, __bf16* __restrict__ xb,
    const float* __restrict__ W1, const float* __restrict__ root1, __bf16* __restrict__ wf,
    const int* __restrict__ h, const int* __restrict__ r, const int* __restrict__ t,
    int* __restrict__ blkcnt, int* __restrict__ blkbuf)
{
    const int gid = blockIdx.x * 256 + threadIdx.x;
    const int nthr = gridDim.x * 256;

    if (gid < 9 * 2048) {
        int mat = gid >> 11, idx = gid & 2047;
        const float* B = (mat < 8) ? (W1 + (size_t)mat * DIM * DIM) : root1;
        int lt = idx & 63, fid = idx >> 6;
        int s = fid >> 3, nt = fid & 7;
        int n = nt * 16 + (lt & 15);
        int kb = s * 32 + (lt >> 4) * 8;
        bf16x8 v;
#pragma unroll
        for (int j = 0; j < 8; ++j) v[j] = (__bf16)B[(kb + j) * DIM + n];
        *reinterpret_cast<bf16x8*>(wf + ((size_t)mat * 2048 + idx) * 8) = v;
    }
    for (int i = gid; i < NN * DIM / 4; i += nthr) {
        int base = i * 4;
        float4 v = *reinterpret_cast<const float4*>(x + base);
        __bf16 o[4] = {(__bf16)v.x, (__bf16)v.y, (__bf16)v.z, (__bf16)v.w};
        *reinterpret_cast<uint2*>(xb + base) = *reinterpret_cast<uint2*>(o);
    }
    // edge loop: bucket append only (one global atomic per edge)
    for (int i = gid; i < NE / 4; i += nthr) {
        int base = i * 4;
        int4 hv = *reinterpret_cast<const int4*>(h + base);
        int4 rv = *reinterpret_cast<const int4*>(r + base);
        int4 tv = *reinterpret_cast<const int4*>(t + base);
#pragma unroll
        for (int j = 0; j < 4; ++j) {
            int te = (j == 0) ? tv.x : (j == 1) ? tv.y : (j == 2) ? tv.z : tv.w;
            int re = (j == 0) ? rv.x : (j == 1) ? rv.y : (j == 2) ? rv.z : rv.w;
            int he = (j == 0) ? hv.x : (j == 1) ? hv.y : (j == 2) ? hv.z : hv.w;
            int blk = te >> 5;
            int pos = atomicAdd(&blkcnt[blk * 16], 1);
            if (pos < CAP) blkbuf[blk * CAP + pos] = ((((te & 31) * NR) + re) << 17) | he;
        }
    }
}

// ---------------- wsum: bucket-based (R4-proven); block 0 zeroes out[] ----------------
__global__ __launch_bounds__(256) void wsum_k(
    const int* __restrict__ blkcnt, const int* __restrict__ blkbuf, float* __restrict__ wsum,
    float* __restrict__ out)
{
    __shared__ int   lcnt[TM * NR];
    __shared__ float linv[TM * NR];
    const int tid = threadIdx.x;
    if (blockIdx.x == 0 && tid < 128) out[tid] = 0.f;
    int n = blkcnt[blockIdx.x * 16];
    if (n > CAP) n = CAP;
    const int* gbuf = blkbuf + (size_t)blockIdx.x * CAP;
    lcnt[tid] = 0;
    __syncthreads();
    int pk0 = -1, pk1 = -1, pk2 = -1, pk3 = -1;
    if (tid < n)       { pk0 = gbuf[tid];       atomicAdd(&lcnt[pk0 >> 17], 1); }
    if (tid + 256 < n) { pk1 = gbuf[tid + 256]; atomicAdd(&lcnt[pk1 >> 17], 1); }
    if (tid + 512 < n) { pk2 = gbuf[tid + 512]; atomicAdd(&lcnt[pk2 >> 17], 1); }
    if (tid + 768 < n) { pk3 = gbuf[tid + 768]; atomicAdd(&lcnt[pk3 >> 17], 1); }
    __syncthreads();
    int c = lcnt[tid];
    linv[tid] = 1.0f / (float)(c > 1 ? c : 1);
    __syncthreads();
    if (pk0 >= 0) atomicAdd(&wsum[(size_t)((pk0 >> 17) & 7) * NN + (pk0 & 0x1FFFF)], linv[pk0 >> 17]);
    if (pk1 >= 0) atomicAdd(&wsum[(size_t)((pk1 >> 17) & 7) * NN + (pk1 & 0x1FFFF)], linv[pk1 >> 17]);
    if (pk2 >= 0) atomicAdd(&wsum[(size_t)((pk2 >> 17) & 7) * NN + (pk2 & 0x1FFFF)], linv[pk2 >> 17]);
    if (pk3 >= 0) atomicAdd(&wsum[(size_t)((pk3 >> 17) & 7) * NN + (pk3 & 0x1FFFF)], linv[pk3 >> 17]);
}

// ---------------- fused layer 1 + layer-2 partials: local CSR + depth-2 walk (R11 EXACT) ----------------
// (256,4) + depth-2 + 64 VGPR + shfl-scan prologue is the measured optimum. Closed directions:
//   R6: min-waves 6 -> VGPR crushed to 40, 266MB spill churn, 140us
//   R8: depth-3 -> scratch spill at fixed 64 VGPR (FETCH +75MB, WRITE +65MB), 130us
//   R5: masked unconditional loads -> +2us (no vmcnt win)
//   R1/R2/R3/R9: restructures -> 2x losses
//   R12: inline-asm prefetch -> runtime abort
//   R13: C++ L2-warm touches -> FETCH +66MB (16MB/XCD resident footprint >> 4MB L2; lines
//        evicted before the walk; every touch pure added traffic), fused 84->101us
__global__ __launch_bounds__(256, 4) void rgcn_fused_k(
    const int* __restrict__ blkcnt, const int* __restrict__ blkbuf,
    const __bf16* __restrict__ xb, const __bf16* __restrict__ wf,
    const float* __restrict__ b1, const float* __restrict__ wsum,
    float* __restrict__ S2P)
{
    __shared__ __attribute__((aligned(16))) __bf16 Atile[2][TM * PAD];  // 17.4 KB (red reuse)
    __shared__ int   loffs[TM * NR + 1];
    __shared__ int   lcnt[TM * NR];
    __shared__ int   cursor[TM * NR];
    __shared__ float invl[TM * NR];
    __shared__ float wsl[NR][TM];
    __shared__ int   wsumS[4];          // per-wave scan sums
    __shared__ int   pkd[CAP];          // heads, sorted by local segment
    const int tid = threadIdx.x;
    const int wave = tid >> 6, lane = tid & 63, quad = lane >> 4;
    const int slot = tid >> 4, sl = tid & 15;   // 16 gather slots x 16 lanes
    const int tbase = blockIdx.x * TM;

    // ---- local CSR build ----
    int n = blkcnt[blockIdx.x * 16];
    if (n > CAP) n = CAP;
    const int* gbuf = blkbuf + (size_t)blockIdx.x * CAP;
    lcnt[tid] = 0;
    __syncthreads();
    int pk0 = -1, pk1 = -1, pk2 = -1, pk3 = -1;
    if (tid < n)       { pk0 = gbuf[tid];       atomicAdd(&lcnt[pk0 >> 17], 1); }
    if (tid + 256 < n) { pk1 = gbuf[tid + 256]; atomicAdd(&lcnt[pk1 >> 17], 1); }
    if (tid + 512 < n) { pk2 = gbuf[tid + 512]; atomicAdd(&lcnt[pk2 >> 17], 1); }
    if (tid + 768 < n) { pk3 = gbuf[tid + 768]; atomicAdd(&lcnt[pk3 >> 17], 1); }
    __syncthreads();
    int v = lcnt[tid];
    // wave-level inclusive scan (shfl, barrier-free) + cross-wave offset (2 barriers total)
    int incl = v;
#pragma unroll
    for (int off = 1; off < 64; off <<= 1) {
        int up = __shfl_up(incl, off, 64);
        if (lane >= off) incl += up;
    }
    if (lane == 63) wsumS[wave] = incl;
    __syncthreads();
    int woff = 0;
#pragma unroll
    for (int w = 0; w < 3; ++w) woff += (w < wave) ? wsumS[w] : 0;
    incl += woff;
    loffs[tid + 1] = incl;               // inclusive
    if (tid == 0) loffs[0] = 0;
    cursor[tid] = incl - v;              // exclusive
    invl[tid] = 1.0f / (float)(v > 1 ? v : 1);
    {
        int rr = tid >> 5, nn = tbase + (tid & 31);
        wsl[rr][tid & 31] = (nn < NN) ? wsum[rr * NN + nn] : 0.f;
    }
    __syncthreads();
    if (pk0 >= 0) { int p = atomicAdd(&cursor[pk0 >> 17], 1); pkd[p] = pk0 & 0x1FFFF; }
    if (pk1 >= 0) { int p = atomicAdd(&cursor[pk1 >> 17], 1); pkd[p] = pk1 & 0x1FFFF; }
    if (pk2 >= 0) { int p = atomicAdd(&cursor[pk2 >> 17], 1); pkd[p] = pk2 & 0x1FFFF; }
    if (pk3 >= 0) { int p = atomicAdd(&cursor[pk3 >> 17], 1); pkd[p] = pk3 & 0x1FFFF; }
    __syncthreads();

    floatx4 C[4];
#pragma unroll
    for (int i = 0; i < 4; ++i) C[i] = (floatx4)0.f;
    const int arow = (wave & 1) * 16 + (lane & 15);   // wave row-strip
    const int ntg0 = (wave >> 1) * 4;                 // wave col-strip (4 nt each)

    // ---- 4 term-pairs: 4 depth-2-pipelined walks (2 rows x 2 terms), 2 A-tiles ----
    for (int tp = 0; tp < 4; ++tp) {
        int st[4], ln[4];
        float a[4][8];
#pragma unroll
        for (int q = 0; q < 4; ++q) {
            int j = (slot + (q >> 1) * 16) * 8 + tp * 2 + (q & 1);
            st[q] = loffs[j];
            ln[q] = loffs[j + 1] - loffs[j];
#pragma unroll
            for (int k = 0; k < 8; ++k) a[q][k] = 0.f;
        }
        int mx = max(max(ln[0], ln[1]), max(ln[2], ln[3]));
        if (mx > 0) {
            bf16x8 ycur[4];
#pragma unroll
            for (int q = 0; q < 4; ++q) {
                if (0 < ln[q]) {
                    int he = pkd[st[q]];
                    ycur[q] = *reinterpret_cast<const bf16x8*>(xb + (size_t)he * DIM + sl * 8);
                }
            }
            for (int p = 0; p < mx; ++p) {
                bf16x8 ynext[4];
#pragma unroll
                for (int q = 0; q < 4; ++q) {
                    if (p + 1 < ln[q]) {
                        int he = pkd[st[q] + p + 1];
                        ynext[q] = *reinterpret_cast<const bf16x8*>(xb + (size_t)he * DIM + sl * 8);
                    }
                }
#pragma unroll
                for (int q = 0; q < 4; ++q) {
                    if (p < ln[q]) {
#pragma unroll
                        for (int k = 0; k < 8; ++k) a[q][k] += (float)ycur[q][k];
                    }
                }
#pragma unroll
                for (int q = 0; q < 4; ++q) ycur[q] = ynext[q];
            }
        }
#pragma unroll
        for (int q = 0; q < 4; ++q) {
            int trow = slot + (q >> 1) * 16;
            float sc = invl[trow * 8 + tp * 2 + (q & 1)];
            bf16x8 out;
#pragma unroll
            for (int k = 0; k < 8; ++k) out[k] = (__bf16)(a[q][k] * sc);
            *reinterpret_cast<bf16x8*>(&Atile[q & 1][trow * PAD + sl * 8]) = out;
        }
        __syncthreads();
#pragma unroll
        for (int u = 0; u < 2; ++u) {
            const __bf16* wterm = wf + (size_t)(tp * 2 + u) * 2048 * 8;
#pragma unroll
            for (int s = 0; s < 4; ++s) {
                bf16x8 af = *reinterpret_cast<const bf16x8*>(&Atile[u][arow * PAD + s * 32 + quad * 8]);
#pragma unroll
                for (int nt = 0; nt < 4; ++nt) {
                    bf16x8 bf = *reinterpret_cast<const bf16x8*>(
                        wterm + (size_t)((s * 8 + ntg0 + nt) * 64 + lane) * 8);
                    C[nt] = __builtin_amdgcn_mfma_f32_16x16x32_bf16(af, bf, C[nt], 0, 0, 0);
                }
            }
        }
        __syncthreads();
    }

    // ---- root term: A row = xb[t] ----
#pragma unroll
    for (int i = 0; i < 2; ++i) {
        int trow = slot + i * 16;
        int t = tbase + trow;
        bf16x8 out;
        if (t < NN) {
            out = *reinterpret_cast<const bf16x8*>(xb + (size_t)t * DIM + sl * 8);
        } else {
#pragma unroll
            for (int j = 0; j < 8; ++j) out[j] = (__bf16)0.f;
        }
        *reinterpret_cast<bf16x8*>(&Atile[0][trow * PAD + sl * 8]) = out;
    }
    __syncthreads();
    {
        const __bf16* wterm = wf + (size_t)8 * 2048 * 8;
#pragma unroll
        for (int s = 0; s < 4; ++s) {
            bf16x8 af = *reinterpret_cast<const bf16x8*>(&Atile[0][arow * PAD + s * 32 + quad * 8]);
#pragma unroll
            for (int nt = 0; nt < 4; ++nt) {
                bf16x8 bf = *reinterpret_cast<const bf16x8*>(
                    wterm + (size_t)((s * 8 + ntg0 + nt) * 64 + lane) * 8);
                C[nt] = __builtin_amdgcn_mfma_f32_16x16x32_bf16(af, bf, C[nt], 0, 0, 0);
            }
        }
    }
    __syncthreads();   // Atile dead -> reuse as reduction scratch

    // ---- epilogue: bias + relu in-register, fused S2/X1 block partials ----
    float* red = reinterpret_cast<float*>(&Atile[0][0]);   // [4][576] = 9.2 KB
    const int rowl0 = (wave & 1) * 16 + quad * 4;
    const int colc = lane & 15;
#pragma unroll
    for (int nt = 0; nt < 4; ++nt) {
        float badd = b1[ntg0 * 16 + nt * 16 + colc];
#pragma unroll
        for (int i = 0; i < 4; ++i) C[nt][i] = fmaxf(C[nt][i] + badd, 0.f);
    }
    float rmask[4];
#pragma unroll
    for (int i = 0; i < 4; ++i) rmask[i] = (tbase + rowl0 + i < NN) ? 1.f : 0.f;
#pragma unroll
    for (int nt = 0; nt < 4; ++nt) {
        float p = rmask[0] * C[nt][0] + rmask[1] * C[nt][1] + rmask[2] * C[nt][2] + rmask[3] * C[nt][3];
        p += __shfl_xor(p, 16);
        p += __shfl_xor(p, 32);
        if (quad == 0) red[wave * 576 + nt * 16 + colc] = p;
    }
#pragma unroll
    for (int rr = 0; rr < NR; ++rr) {
        float w0 = wsl[rr][rowl0], w1 = wsl[rr][rowl0 + 1];
        float w2 = wsl[rr][rowl0 + 2], w3 = wsl[rr][rowl0 + 3];
#pragma unroll
        for (int nt = 0; nt < 4; ++nt) {
            float p = w0 * C[nt][0] + w1 * C[nt][1] + w2 * C[nt][2] + w3 * C[nt][3];
            p += __shfl_xor(p, 16);
            p += __shfl_xor(p, 32);
            if (quad == 0) red[wave * 576 + 64 + rr * 64 + nt * 16 + colc] = p;
        }
    }
    __syncthreads();
    for (int j = tid; j < 1152; j += 256) {
        int rr = j >> 7, c = j & 127;          // rr==8 -> X1
        int u = c >> 6, cc = c & 63;
        int o = (rr < 8) ? (64 + rr * 64 + cc) : cc;
        S2P[(size_t)blockIdx.x * 1152 + j] = red[(u * 2) * 576 + o] + red[(u * 2 + 1) * 576 + o];
    }
}

// ---------------- reduce S2P[NB][1152] -> S2X1[1152] (atomic finish, 63 stripes of 25) ----------------
__global__ void s2red_k(const float* __restrict__ S2P, float* __restrict__ S2X1) {
    int cb = blockIdx.x % 5, stripe = blockIdx.x / 5;
    int c = cb * 256 + threadIdx.x;
    if (c >= 1152) return;
    int b0 = stripe * 25, b1 = min(NB, b0 + 25);
    if (b0 >= NB) return;
    float s0 = 0.f, s1 = 0.f;
    int b = b0;
    for (; b + 1 < b1; b += 2) {
        s0 += S2P[(size_t)b * 1152 + c];
        s1 += S2P[(size_t)(b + 1) * 1152 + c];
    }
    if (b < b1) s0 += S2P[(size_t)b * 1152 + c];
    atomicAdd(&S2X1[c], s0 + s1);
}

// ---------------- final: out = (S2.W2 + X1.root2)/N + b2 (72 blocks, R7-proven) ----------------
__global__ __launch_bounds__(256) void final_k(
    const float* __restrict__ S2X1, const float* __restrict__ W2,
    const float* __restrict__ root2, const float* __restrict__ b2, float* __restrict__ out)
{
    __shared__ float red[256];
    const int o = threadIdx.x & 127, jj = threadIdx.x >> 7;   // 2 j-groups of 8
    const int j0 = blockIdx.x * 16 + jj * 8;
    float s = 0.f;
#pragma unroll
    for (int k = 0; k < 8; ++k) {
        int j = j0 + k;
        float v = S2X1[j];
        float w = (j < 1024) ? W2[(size_t)j * DIM + o] : root2[(size_t)(j - 1024) * DIM + o];
        s += v * w;
    }
    red[threadIdx.x] = s;
    __syncthreads();
    if (jj == 0) {
        float add = (red[o] + red[o + 128]) * (1.0f / NN);
        if (blockIdx.x == 0) add += b2[o];
        atomicAdd(&out[o], add);
    }
}

extern "C" void kernel_launch(void* const* d_in, const int* in_sizes, int n_in,
                              void* d_out, int out_size, void* d_ws, size_t ws_size,
                              hipStream_t stream)
{
    const int*   h     = (const int*)d_in[0];
    const int*   r     = (const int*)d_in[1];
    const int*   t     = (const int*)d_in[2];
    const float* x_emb = (const float*)d_in[3];
    const float* W1    = (const float*)d_in[4];
    const float* root1 = (const float*)d_in[5];
    const float* b1    = (const float*)d_in[6];
    const float* W2    = (const float*)d_in[7];
    const float* root2 = (const float*)d_in[8];
    const float* b2    = (const float*)d_in[9];

    float* ws     = (float*)d_ws;
    float* wsum   = ws + OFF_WSUM;
    float* S2     = ws + OFF_S2;      // 1024 S2 + 128 X1 contiguous
    int*   blkcnt = (int*)(ws + OFF_BCNT);
    int*   blkbuf = (int*)(ws + OFF_BBUF);
    __bf16* xb    = (__bf16*)(ws + OFF_XB);
    __bf16* wf    = (__bf16*)(ws + OFF_WF);
    float* S2P    = ws + OFF_S2P;

    // zero wsum + S2X1 + blkcnt (1.7 MB); d_out zeroed inside wsum_k
    hipMemsetAsync(ws, 0, (size_t)426160 * sizeof(float), stream);

    // merged cast + weight-frag + bucket-assign (2048 blocks: ~8-blocks/CU residency)
    prep_k<<<2048, 256, 0, stream>>>(x_emb, xb, W1, root1, wf, h, r, t, blkcnt, blkbuf);

    // wsum from buckets (+ out zero)
    wsum_k<<<NB, 256, 0, stream>>>(blkcnt, blkbuf, wsum, (float*)d_out);

    // fused layer 1 + layer-2 partials: R11-exact (converged config)
    rgcn_fused_k<<<NB, 256, 0, stream>>>(blkcnt, blkbuf, xb, wf, b1, wsum, S2P);

    s2red_k<<<315, 256, 0, stream>>>(S2P, S2);
    final_k<<<72, 256, 0, stream>>>(S2, W2, root2, b2, (float*)d_out);
}